// Round 10
// baseline (143.446 us; speedup 1.0000x reference)
//
#include <hip/hip_runtime.h>
#include <hip/hip_bf16.h>

#define B 4
#define S 2048
#define D 128
#define H 4
#define HD 32
#define D2 256
#define BSD (B*S*D)   // 1048576

#define LDK 40    // k LDS row stride (bf16 units), 80B
#define LDV 72    // v^T LDS row stride (bf16 units), 144B
#define LDSC 72   // sc LDS row stride (bf16 units), 144B
#define LDX 136   // xs LDS row stride (bf16 units)
#define LDH 264   // hsb LDS row stride (bf16 units)

typedef __attribute__((ext_vector_type(8))) short bf16x8;
typedef __attribute__((ext_vector_type(4))) short bf16x4;
typedef __attribute__((ext_vector_type(4))) float f32x4;

__device__ __forceinline__ float silu_f(float z){ return z / (1.f + __expf(-z)); }
__device__ __forceinline__ short f2bfs(float f){
    __hip_bfloat16 h = __float2bfloat16(f);
    return *reinterpret_cast<short*>(&h);
}
__device__ __forceinline__ float bfs2f(short s){
    __hip_bfloat16 h = *reinterpret_cast<__hip_bfloat16*>(&s);
    return __bfloat162float(h);
}

// ---------------------------------------------------------------------------
// Kernel 0: transpose all weights to bf16 W^T[n][k]. 448 blocks x 256.
// ---------------------------------------------------------------------------
__global__ __launch_bounds__(256) void k_wt(
    const float* __restrict__ Wq, const float* __restrict__ Wk,
    const float* __restrict__ Wv, const float* __restrict__ Wu,
    const float* __restrict__ Wf,
    short* __restrict__ wqt, short* __restrict__ wkt, short* __restrict__ wvt,
    short* __restrict__ wut, short* __restrict__ wft)
{
    int e = blockIdx.x * 256 + threadIdx.x;
    if (e < 16384) { int n = e >> 7, k = e & 127; wqt[e] = f2bfs(Wq[k * D  + n]); return; }
    e -= 16384;
    if (e < 16384) { int n = e >> 7, k = e & 127; wkt[e] = f2bfs(Wk[k * D  + n]); return; }
    e -= 16384;
    if (e < 16384) { int n = e >> 7, k = e & 127; wvt[e] = f2bfs(Wv[k * D  + n]); return; }
    e -= 16384;
    if (e < 32768) { int n = e >> 7, k = e & 127; wut[e] = f2bfs(Wu[k * D2 + n]); return; }
    e -= 32768;
    { int n = e >> 8, k = e & 255; wft[e] = f2bfs(Wf[k * D + n]); }
}

// ---------------------------------------------------------------------------
// Kernel 1 (MFMA): projections. Grid (512, 2): 16 rows x 320-col half.
// Wave w covers cols [by*320 + w*80, +80) = 5 tiles of 16. 4 blocks/CU.
// ---------------------------------------------------------------------------
__global__ __launch_bounds__(256) void k_qkvu(
    const float* __restrict__ x,
    const short* __restrict__ wqt, const short* __restrict__ wkt,
    const short* __restrict__ wvt, const short* __restrict__ wut,
    const float* __restrict__ bq, const float* __restrict__ bk,
    const float* __restrict__ bv, const float* __restrict__ bu,
    short* __restrict__ qb, short* __restrict__ kb, short* __restrict__ vtb,
    short* __restrict__ ub)
{
    __shared__ short xs[16 * LDX] __attribute__((aligned(16)));
    const int row0 = blockIdx.x * 16;
    const int by   = blockIdx.y;
    const int tid  = threadIdx.x;
    const int w    = tid >> 6;
    const int lane = tid & 63;
    const int q16  = lane >> 4;
    const int l15  = lane & 15;

    // stage X[16][128] fp32 -> bf16 LDS once
    #pragma unroll
    for (int i = 0; i < 2; ++i) {
        int quad = tid + i * 256;            // 0..511
        int row = quad >> 5, c4 = (quad & 31) * 4;
        f32x4 xv = *(const f32x4*)(x + (row0 + row) * D + c4);
        short tmp[4];
        #pragma unroll
        for (int j = 0; j < 4; ++j) tmp[j] = f2bfs(xv[j]);
        *(bf16x4*)(xs + row * LDX + c4) = *(bf16x4*)tmp;
    }
    __syncthreads();

    bf16x8 af[4];
    #pragma unroll
    for (int ks = 0; ks < 4; ++ks)
        af[ks] = *(const bf16x8*)(xs + l15 * LDX + ks * 32 + q16 * 8);

    const int bb   = row0 / S;
    const int mloc = (row0 % S) + q16 * 4;

    #pragma unroll
    for (int t = 0; t < 5; ++t) {
        const int g = by * 320 + w * 80 + t * 16;   // global out-col tile start
        const short* WT; const float* bias; int base; int kind;
        if (g < 128)      { WT = wqt; bias = bq; base = 0;   kind = 0; }
        else if (g < 256) { WT = wkt; bias = bk; base = 128; kind = 1; }
        else if (g < 384) { WT = wvt; bias = bv; base = 256; kind = 2; }
        else              { WT = wut; bias = bu; base = 384; kind = 3; }
        const int nloc = g - base;
        f32x4 acc = {0.f, 0.f, 0.f, 0.f};
        #pragma unroll
        for (int ks = 0; ks < 4; ++ks) {
            bf16x8 bfr = *(const bf16x8*)(WT + (nloc + l15) * D + ks * 32 + q16 * 8);
            acc = __builtin_amdgcn_mfma_f32_16x16x32_bf16(af[ks], bfr, acc, 0, 0, 0);
        }
        const float bcol = bias[nloc + l15];
        if (kind == 2) {
            short tmp[4];
            #pragma unroll
            for (int r = 0; r < 4; ++r) tmp[r] = f2bfs(silu_f(acc[r] + bcol));
            *(bf16x4*)(vtb + (bb * D + nloc + l15) * S + mloc) = *(bf16x4*)tmp;
        } else if (kind == 3) {
            #pragma unroll
            for (int r = 0; r < 4; ++r)
                ub[(row0 + q16 * 4 + r) * D2 + nloc + l15] = f2bfs(acc[r] + bcol);
        } else {
            short* dst = (kind == 0) ? qb : kb;
            #pragma unroll
            for (int r = 0; r < 4; ++r)
                dst[(row0 + q16 * 4 + r) * D + nloc + l15] = f2bfs(silu_f(acc[r] + bcol));
        }
    }
}

// ---------------------------------------------------------------------------
// Kernel 2 (fused, MFMA): attention + pos-attn, software-pipelined staging
// (preload it+1 into registers during compute of it). Partials stored bf16.
// ---------------------------------------------------------------------------
__global__ __launch_bounds__(256) void k_mix(
    const short* __restrict__ qb, const short* __restrict__ kb,
    const short* __restrict__ vtb, const float* __restrict__ pos_w,
    short* __restrict__ as_part, short* __restrict__ ap)
{
    __shared__ char smem[20544] __attribute__((aligned(16)));
    const int tid  = threadIdx.x;
    const int w    = tid >> 6;
    const int lane = tid & 63;
    const int q16  = lane >> 4;
    const int l15  = lane & 15;
    const int bid  = blockIdx.x;

    if (bid < 1024) {
        short* ks  = (short*)smem;
        short* vt  = (short*)(smem + 5120);
        short* scw = (short*)(smem + 9728) + w * 16 * LDSC;
        const int att = bid;
        const int nt  = 31 - (att >> 5);
        const int sub = att & 31;
        const int h   = sub & 3;
        const int b   = (sub >> 2) & 3;
        const int zz  = sub >> 4;
        const int n0  = nt * 64;

        bf16x8 qfrag = *(const bf16x8*)(qb + (b * S + n0 + w * 16 + l15) * D + h * HD + q16 * 8);
        f32x4 o0 = {0.f, 0.f, 0.f, 0.f};
        f32x4 o1 = {0.f, 0.f, 0.f, 0.f};

        const int nm    = nt + 1;
        const int half1 = (nm + 1) >> 1;
        const int it_lo = zz ? half1 : 0;
        const int it_hi = zz ? nm : half1;

        // per-thread staging coordinates
        const int krow = tid >> 2, kc8 = tid & 3;
        const int vd   = tid >> 3, vm8 = tid & 7;
        const short* kp_base = kb  + (b * S + krow) * D + h * HD + kc8 * 8;
        const short* vp_base = vtb + (b * D + h * HD + vd) * S + vm8 * 8;

        // preload first tile (if range empty, reads a valid dummy tile)
        bf16x8 kreg = *(const bf16x8*)(kp_base + it_lo * 64 * D);
        bf16x8 vreg = *(const bf16x8*)(vp_base + it_lo * 64);

        for (int it = it_lo; it < it_hi; ++it) {
            const int m0 = it * 64;
            __syncthreads();
            *(bf16x8*)(ks + krow * LDK + kc8 * 8) = kreg;
            *(bf16x8*)(vt + vd * LDV + vm8 * 8)   = vreg;
            __syncthreads();
            if (it + 1 < it_hi) {      // preload next tile; latency overlaps compute
                kreg = *(const bf16x8*)(kp_base + (it + 1) * 64 * D);
                vreg = *(const bf16x8*)(vp_base + (it + 1) * 64);
            }
            if (it != nt) {
                // non-diagonal: no masking
                #pragma unroll
                for (int t = 0; t < 4; ++t) {
                    bf16x8 kf = *(const bf16x8*)(ks + (t * 16 + l15) * LDK + q16 * 8);
                    f32x4 sacc = {0.f, 0.f, 0.f, 0.f};
                    sacc = __builtin_amdgcn_mfma_f32_16x16x32_bf16(qfrag, kf, sacc, 0, 0, 0);
                    #pragma unroll
                    for (int r = 0; r < 4; ++r) {
                        float sv = sacc[r] * 0.17677669529663687f;   // 1/sqrt(32)
                        float wgt = silu_f(sv * sv);
                        scw[(q16 * 4 + r) * LDSC + t * 16 + l15] = f2bfs(wgt);
                    }
                }
            } else {
                // diagonal tile: causal mask
                const int n_gb = n0 + w * 16 + q16 * 4;
                #pragma unroll
                for (int t = 0; t < 4; ++t) {
                    bf16x8 kf = *(const bf16x8*)(ks + (t * 16 + l15) * LDK + q16 * 8);
                    f32x4 sacc = {0.f, 0.f, 0.f, 0.f};
                    sacc = __builtin_amdgcn_mfma_f32_16x16x32_bf16(qfrag, kf, sacc, 0, 0, 0);
                    const int m_g = m0 + t * 16 + l15;
                    #pragma unroll
                    for (int r = 0; r < 4; ++r) {
                        float sv = sacc[r] * 0.17677669529663687f;
                        float wgt = silu_f(sv * sv);
                        if (m_g > n_gb + r) wgt = 0.f;
                        scw[(q16 * 4 + r) * LDSC + t * 16 + l15] = f2bfs(wgt);
                    }
                }
            }
            #pragma unroll
            for (int kt = 0; kt < 2; ++kt) {
                bf16x8 pf = *(const bf16x8*)(scw + l15 * LDSC + kt * 32 + q16 * 8);
                bf16x8 v0 = *(const bf16x8*)(vt + l15 * LDV        + kt * 32 + q16 * 8);
                bf16x8 v1 = *(const bf16x8*)(vt + (16 + l15) * LDV + kt * 32 + q16 * 8);
                o0 = __builtin_amdgcn_mfma_f32_16x16x32_bf16(pf, v0, o0, 0, 0, 0);
                o1 = __builtin_amdgcn_mfma_f32_16x16x32_bf16(pf, v1, o1, 0, 0, 0);
            }
        }
        short* dst = as_part + zz * BSD;
        const int nrow = n0 + w * 16 + q16 * 4;
        #pragma unroll
        for (int r = 0; r < 4; ++r) {
            dst[(b * S + nrow + r) * D + h * HD + l15]      = f2bfs(o0[r]);
            dst[(b * S + nrow + r) * D + h * HD + 16 + l15] = f2bfs(o1[r]);
        }
    } else {
        short* pw = (short*)smem;
        short* vt = (short*)(smem + 2112);
        const int pid = bid - 1024;
        const int n0  = (pid >> 3) * 32;
        const int sub = pid & 7;
        const int b   = sub >> 1;
        const int z   = sub & 1;
        const int s   = w >> 1;
        const int dh  = w & 1;

        const int base_g = 2016 + z * 1024 - n0;
        for (int i = tid; i < 1055; i += 256) pw[i] = f2bfs(pos_w[base_g + i]);

        f32x4 acc[4];
        #pragma unroll
        for (int dt = 0; dt < 4; ++dt) acc[dt] = (f32x4){0.f, 0.f, 0.f, 0.f};

        // per-thread staging coords: 4 vectors per iteration
        int sd[4], sm8[4];
        const short* vp[4];
        #pragma unroll
        for (int i = 0; i < 4; ++i) {
            int e = tid + i * 256;
            sd[i] = e >> 3; sm8[i] = e & 7;
            vp[i] = vtb + (b * D + sd[i]) * S + z * 1024 + sm8[i] * 8;
        }
        bf16x8 vreg[4];
        #pragma unroll
        for (int i = 0; i < 4; ++i) vreg[i] = *(const bf16x8*)(vp[i]);

        for (int mt = 0; mt < 16; ++mt) {
            __syncthreads();
            #pragma unroll
            for (int i = 0; i < 4; ++i)
                *(bf16x8*)(vt + sd[i] * LDV + sm8[i] * 8) = vreg[i];
            __syncthreads();
            if (mt + 1 < 16) {
                #pragma unroll
                for (int i = 0; i < 4; ++i)
                    vreg[i] = *(const bf16x8*)(vp[i] + (mt + 1) * 64);
            }
            #pragma unroll
            for (int kt = 0; kt < 2; ++kt) {
                bf16x8 af;
                int idx0 = mt * 64 + kt * 32 + q16 * 8 + 31 - s * 16 - l15;
                #pragma unroll
                for (int j = 0; j < 8; ++j) af[j] = pw[idx0 + j];
                #pragma unroll
                for (int dt = 0; dt < 4; ++dt) {
                    bf16x8 bv = *(const bf16x8*)(vt + (dh * 64 + dt * 16 + l15) * LDV + kt * 32 + q16 * 8);
                    acc[dt] = __builtin_amdgcn_mfma_f32_16x16x32_bf16(af, bv, acc[dt], 0, 0, 0);
                }
            }
        }
        short* dst = ap + z * BSD;
        const int nrow = n0 + s * 16 + q16 * 4;
        #pragma unroll
        for (int dt = 0; dt < 4; ++dt)
            #pragma unroll
            for (int r = 0; r < 4; ++r)
                dst[(b * S + nrow + r) * D + dh * 64 + dt * 16 + l15] = f2bfs(acc[dt][r]);
    }
}

// ---------------------------------------------------------------------------
// Kernel 3 (MFMA): 1024 blocks x 8 rows. Phase A: LN (32 lanes/row) -> h bf16
// LDS. Phase B: h[8][256] @ Wf^T via MFMA (rows 8..15 zeroed), relu+residual.
// Partials read as bf16.
// ---------------------------------------------------------------------------
__global__ __launch_bounds__(256) void k_final(
    const short* __restrict__ as_part, const short* __restrict__ ap,
    const short* __restrict__ ub, const short* __restrict__ wft,
    const float* __restrict__ gamma, const float* __restrict__ beta,
    const float* __restrict__ bfb,
    const float* __restrict__ x, float* __restrict__ out)
{
    __shared__ short hsb[16 * LDH] __attribute__((aligned(16)));
    const int tid  = threadIdx.x;
    const int row0 = blockIdx.x * 8;

    // zero rows 8..15 (MFMA A-frag padding)
    for (int i = tid; i < 8 * LDH; i += 256) hsb[8 * LDH + i] = 0;

    // ---- Phase A: LN + u-mult, 32 lanes per row ----
    {
        const int row = tid >> 5;            // 0..7
        const int c   = tid & 31;
        float av[8];
        float s1 = 0.f, s2 = 0.f;
        #pragma unroll
        for (int j = 0; j < 8; ++j) {
            int col = c + j * 32;
            float v_;
            if (col < 128)
                v_ = bfs2f(as_part[(row0 + row) * D + col]) +
                     bfs2f(as_part[BSD + (row0 + row) * D + col]);
            else {
                int c2 = col - 128;
                v_ = bfs2f(ap[(row0 + row) * D + c2]) +
                     bfs2f(ap[BSD + (row0 + row) * D + c2]);
            }
            av[j] = v_;
            s1 += v_;
            s2 += v_ * v_;
        }
        #pragma unroll
        for (int off = 1; off < 32; off <<= 1) {
            s1 += __shfl_xor(s1, off);
            s2 += __shfl_xor(s2, off);
        }
        float mu  = s1 * (1.f / 256.f);
        float var = s2 * (1.f / 256.f) - mu * mu;
        float rs  = rsqrtf(var + 1e-3f);
        #pragma unroll
        for (int j = 0; j < 8; ++j) {
            int col = c + j * 32;
            float an = (av[j] - mu) * rs * gamma[col] + beta[col];
            float h  = bfs2f(ub[(row0 + row) * D2 + col]) * an;
            hsb[row * LDH + col] = f2bfs(h);
        }
    }
    __syncthreads();

    // ---- Phase B: wave w covers 32 out-cols; only rows 0..7 stored ----
    const int w    = tid >> 6;
    const int lane = tid & 63;
    const int q16  = lane >> 4;
    const int l15  = lane & 15;
    f32x4 o[2];
    o[0] = (f32x4){0.f, 0.f, 0.f, 0.f};
    o[1] = (f32x4){0.f, 0.f, 0.f, 0.f};
    #pragma unroll
    for (int ks = 0; ks < 8; ++ks) {
        bf16x8 af = *(const bf16x8*)(hsb + l15 * LDH + ks * 32 + q16 * 8);
        #pragma unroll
        for (int ci = 0; ci < 2; ++ci) {
            const int ct = w * 2 + ci;
            bf16x8 bfr = *(const bf16x8*)(wft + (ct * 16 + l15) * D2 + ks * 32 + q16 * 8);
            o[ci] = __builtin_amdgcn_mfma_f32_16x16x32_bf16(af, bfr, o[ci], 0, 0, 0);
        }
    }
    if (q16 < 2) {
        #pragma unroll
        for (int ci = 0; ci < 2; ++ci) {
            const int n = (w * 2 + ci) * 16 + l15;
            const float bfv = bfb[n];
            #pragma unroll
            for (int r = 0; r < 4; ++r) {
                const int row = row0 + q16 * 4 + r;
                float oo = o[ci][r] + bfv;
                oo = fmaxf(oo, 0.f);
                oo += x[row * D + n];
                out[row * D + n] = oo;
            }
        }
    }
}

// ---------------------------------------------------------------------------
extern "C" void kernel_launch(void* const* d_in, const int* in_sizes, int n_in,
                              void* d_out, int out_size, void* d_ws, size_t ws_size,
                              hipStream_t stream)
{
    const float* x     = (const float*)d_in[0];
    const float* Wq    = (const float*)d_in[1];
    const float* bq    = (const float*)d_in[2];
    const float* Wk    = (const float*)d_in[3];
    const float* bk    = (const float*)d_in[4];
    const float* Wv    = (const float*)d_in[5];
    const float* bv    = (const float*)d_in[6];
    const float* Wu    = (const float*)d_in[7];
    const float* bu    = (const float*)d_in[8];
    const float* pos_w = (const float*)d_in[9];
    const float* gamma = (const float*)d_in[10];
    const float* beta  = (const float*)d_in[11];
    const float* Wf    = (const float*)d_in[12];
    const float* bfb   = (const float*)d_in[13];
    float* out = (float*)d_out;

    // workspace (~18.2 MB; 28 MB proven safe):
    char* p = (char*)d_ws;
    short* qb      = (short*)p;  p += (size_t)BSD * 2;        // 2 MB bf16 q
    short* kb      = (short*)p;  p += (size_t)BSD * 2;        // 2 MB bf16 k
    short* vtb     = (short*)p;  p += (size_t)BSD * 2;        // 2 MB bf16 v^T [B][D][S]
    short* ubuf    = (short*)p;  p += (size_t)2 * BSD * 2;    // 4 MB bf16 u
    short* as_part = (short*)p;  p += (size_t)2 * BSD * 2;    // 4 MB bf16 self partials x2
    short* ap      = (short*)p;  p += (size_t)2 * BSD * 2;    // 4 MB bf16 pos partials x2
    short* wqt     = (short*)p;  p += (size_t)D * D * 2;      // 32 KB bf16 Wq^T
    short* wkt     = (short*)p;  p += (size_t)D * D * 2;      // 32 KB bf16 Wk^T
    short* wvt     = (short*)p;  p += (size_t)D * D * 2;      // 32 KB bf16 Wv^T
    short* wut     = (short*)p;  p += (size_t)D2 * D * 2;     // 64 KB bf16 Wu^T
    short* wft     = (short*)p;  p += (size_t)D * D2 * 2;     // 64 KB bf16 Wf^T

    k_wt   <<<dim3(448),    256, 0, stream>>>(Wq, Wk, Wv, Wu, Wf, wqt, wkt, wvt, wut, wft);
    k_qkvu <<<dim3(512, 2), 256, 0, stream>>>(x, wqt, wkt, wvt, wut, bq, bk, bv, bu, qb, kb, vtb, ubuf);
    k_mix  <<<dim3(1536),   256, 0, stream>>>(qb, kb, vtb, pos_w, as_part, ap);
    k_final<<<dim3(1024),   256, 0, stream>>>(as_part, ap, ubuf, wft, gamma, beta, bfb, x, out);
}

// Round 11
// 137.786 us; speedup vs baseline: 1.0411x; 1.0411x over previous
//
#include <hip/hip_runtime.h>
#include <hip/hip_bf16.h>

#define B 4
#define S 2048
#define D 128
#define H 4
#define HD 32
#define D2 256
#define BSD (B*S*D)   // 1048576

#define LDK 40    // k LDS row stride (bf16 units), 80B
#define LDV 72    // v^T LDS row stride (bf16 units), 144B
#define LDSC 72   // sc LDS row stride (bf16 units), 144B
#define LDX 136   // xs LDS row stride (bf16 units)
#define LDH 264   // hsb LDS row stride (bf16 units)

typedef __attribute__((ext_vector_type(8))) short bf16x8;
typedef __attribute__((ext_vector_type(4))) short bf16x4;
typedef __attribute__((ext_vector_type(4))) float f32x4;

__device__ __forceinline__ float silu_f(float z){ return z / (1.f + __expf(-z)); }
__device__ __forceinline__ short f2bfs(float f){
    __hip_bfloat16 h = __float2bfloat16(f);
    return *reinterpret_cast<short*>(&h);
}
__device__ __forceinline__ float bfs2f(short s){
    __hip_bfloat16 h = *reinterpret_cast<__hip_bfloat16*>(&s);
    return __bfloat162float(h);
}

// ---------------------------------------------------------------------------
// Kernel 0: transpose all weights to bf16 W^T[n][k]. 448 blocks x 256.
// ---------------------------------------------------------------------------
__global__ __launch_bounds__(256) void k_wt(
    const float* __restrict__ Wq, const float* __restrict__ Wk,
    const float* __restrict__ Wv, const float* __restrict__ Wu,
    const float* __restrict__ Wf,
    short* __restrict__ wqt, short* __restrict__ wkt, short* __restrict__ wvt,
    short* __restrict__ wut, short* __restrict__ wft)
{
    int e = blockIdx.x * 256 + threadIdx.x;
    if (e < 16384) { int n = e >> 7, k = e & 127; wqt[e] = f2bfs(Wq[k * D  + n]); return; }
    e -= 16384;
    if (e < 16384) { int n = e >> 7, k = e & 127; wkt[e] = f2bfs(Wk[k * D  + n]); return; }
    e -= 16384;
    if (e < 16384) { int n = e >> 7, k = e & 127; wvt[e] = f2bfs(Wv[k * D  + n]); return; }
    e -= 16384;
    if (e < 32768) { int n = e >> 7, k = e & 127; wut[e] = f2bfs(Wu[k * D2 + n]); return; }
    e -= 32768;
    { int n = e >> 8, k = e & 255; wft[e] = f2bfs(Wf[k * D + n]); }
}

// ---------------------------------------------------------------------------
// Kernel 1 (MFMA): projections. Grid (512, 2): 16 rows x 320-col half.
// ---------------------------------------------------------------------------
__global__ __launch_bounds__(256) void k_qkvu(
    const float* __restrict__ x,
    const short* __restrict__ wqt, const short* __restrict__ wkt,
    const short* __restrict__ wvt, const short* __restrict__ wut,
    const float* __restrict__ bq, const float* __restrict__ bk,
    const float* __restrict__ bv, const float* __restrict__ bu,
    short* __restrict__ qb, short* __restrict__ kb, short* __restrict__ vtb,
    short* __restrict__ ub)
{
    __shared__ short xs[16 * LDX] __attribute__((aligned(16)));
    const int row0 = blockIdx.x * 16;
    const int by   = blockIdx.y;
    const int tid  = threadIdx.x;
    const int w    = tid >> 6;
    const int lane = tid & 63;
    const int q16  = lane >> 4;
    const int l15  = lane & 15;

    #pragma unroll
    for (int i = 0; i < 2; ++i) {
        int quad = tid + i * 256;
        int row = quad >> 5, c4 = (quad & 31) * 4;
        f32x4 xv = *(const f32x4*)(x + (row0 + row) * D + c4);
        short tmp[4];
        #pragma unroll
        for (int j = 0; j < 4; ++j) tmp[j] = f2bfs(xv[j]);
        *(bf16x4*)(xs + row * LDX + c4) = *(bf16x4*)tmp;
    }
    __syncthreads();

    bf16x8 af[4];
    #pragma unroll
    for (int ks = 0; ks < 4; ++ks)
        af[ks] = *(const bf16x8*)(xs + l15 * LDX + ks * 32 + q16 * 8);

    const int bb   = row0 / S;
    const int mloc = (row0 % S) + q16 * 4;

    #pragma unroll
    for (int t = 0; t < 5; ++t) {
        const int g = by * 320 + w * 80 + t * 16;
        const short* WT; const float* bias; int base; int kind;
        if (g < 128)      { WT = wqt; bias = bq; base = 0;   kind = 0; }
        else if (g < 256) { WT = wkt; bias = bk; base = 128; kind = 1; }
        else if (g < 384) { WT = wvt; bias = bv; base = 256; kind = 2; }
        else              { WT = wut; bias = bu; base = 384; kind = 3; }
        const int nloc = g - base;
        f32x4 acc = {0.f, 0.f, 0.f, 0.f};
        #pragma unroll
        for (int ks = 0; ks < 4; ++ks) {
            bf16x8 bfr = *(const bf16x8*)(WT + (nloc + l15) * D + ks * 32 + q16 * 8);
            acc = __builtin_amdgcn_mfma_f32_16x16x32_bf16(af[ks], bfr, acc, 0, 0, 0);
        }
        const float bcol = bias[nloc + l15];
        if (kind == 2) {
            short tmp[4];
            #pragma unroll
            for (int r = 0; r < 4; ++r) tmp[r] = f2bfs(silu_f(acc[r] + bcol));
            *(bf16x4*)(vtb + (bb * D + nloc + l15) * S + mloc) = *(bf16x4*)tmp;
        } else if (kind == 3) {
            #pragma unroll
            for (int r = 0; r < 4; ++r)
                ub[(row0 + q16 * 4 + r) * D2 + nloc + l15] = f2bfs(acc[r] + bcol);
        } else {
            short* dst = (kind == 0) ? qb : kb;
            #pragma unroll
            for (int r = 0; r < 4; ++r)
                dst[(row0 + q16 * 4 + r) * D + nloc + l15] = f2bfs(silu_f(acc[r] + bcol));
        }
    }
}

// ---------------------------------------------------------------------------
// Kernel 2 (fused, MFMA): attention + pos-attn.
// Attention: TRANSPOSED score MFMA (A=kf, B=qfrag) -> D[key][query], so the
// sc tile is written as 4x ds_write_b64 per lane (was 16x b16 scatter).
// Pos: pw staged f32; A-frag via merged ds_read2_b32 + v_perm packs.
// ---------------------------------------------------------------------------
__global__ __launch_bounds__(256) void k_mix(
    const short* __restrict__ qb, const short* __restrict__ kb,
    const short* __restrict__ vtb, const float* __restrict__ pos_w,
    short* __restrict__ as_part, short* __restrict__ ap)
{
    __shared__ char smem[22656] __attribute__((aligned(16)));
    const int tid  = threadIdx.x;
    const int w    = tid >> 6;
    const int lane = tid & 63;
    const int q16  = lane >> 4;
    const int l15  = lane & 15;
    const int bid  = blockIdx.x;

    if (bid < 1024) {
        short* ks  = (short*)smem;                              // 5120 B
        short* vt  = (short*)(smem + 5120);                     // 4608 B
        short* scw = (short*)(smem + 9728) + w * 16 * LDSC;     // 4x2304 B
        const int att = bid;
        const int nt  = 31 - (att >> 5);
        const int sub = att & 31;
        const int h   = sub & 3;
        const int b   = (sub >> 2) & 3;
        const int zz  = sub >> 4;
        const int n0  = nt * 64;

        bf16x8 qfrag = *(const bf16x8*)(qb + (b * S + n0 + w * 16 + l15) * D + h * HD + q16 * 8);
        f32x4 o0 = {0.f, 0.f, 0.f, 0.f};
        f32x4 o1 = {0.f, 0.f, 0.f, 0.f};

        const int nm    = nt + 1;
        const int half1 = (nm + 1) >> 1;
        const int it_lo = zz ? half1 : 0;
        const int it_hi = zz ? nm : half1;

        const int krow = tid >> 2, kc8 = tid & 3;
        const int vd   = tid >> 3, vm8 = tid & 7;
        const short* kp_base = kb  + (b * S + krow) * D + h * HD + kc8 * 8;
        const short* vp_base = vtb + (b * D + h * HD + vd) * S + vm8 * 8;

        bf16x8 kreg = *(const bf16x8*)(kp_base + it_lo * 64 * D);
        bf16x8 vreg = *(const bf16x8*)(vp_base + it_lo * 64);

        for (int it = it_lo; it < it_hi; ++it) {
            const int m0 = it * 64;
            __syncthreads();
            *(bf16x8*)(ks + krow * LDK + kc8 * 8) = kreg;
            *(bf16x8*)(vt + vd * LDV + vm8 * 8)   = vreg;
            __syncthreads();
            if (it + 1 < it_hi) {
                kreg = *(const bf16x8*)(kp_base + (it + 1) * 64 * D);
                vreg = *(const bf16x8*)(vp_base + (it + 1) * 64);
            }
            if (it != nt) {
                // non-diagonal: no masking. S^T: D[key=q16*4+r (in t-tile)][query=l15]
                #pragma unroll
                for (int t = 0; t < 4; ++t) {
                    bf16x8 kf = *(const bf16x8*)(ks + (t * 16 + l15) * LDK + q16 * 8);
                    f32x4 sacc = {0.f, 0.f, 0.f, 0.f};
                    sacc = __builtin_amdgcn_mfma_f32_16x16x32_bf16(kf, qfrag, sacc, 0, 0, 0);
                    short tmp[4];
                    #pragma unroll
                    for (int r = 0; r < 4; ++r) {
                        float sv = sacc[r] * 0.17677669529663687f;   // 1/sqrt(32)
                        tmp[r] = f2bfs(silu_f(sv * sv));
                    }
                    // sc[query=l15][key=t*16+q16*4 + r], r contiguous -> b64
                    *(bf16x4*)(scw + l15 * LDSC + t * 16 + q16 * 4) = *(bf16x4*)tmp;
                }
            } else {
                // diagonal tile: causal mask (key > query -> 0)
                const int query_g = n0 + w * 16 + l15;
                #pragma unroll
                for (int t = 0; t < 4; ++t) {
                    bf16x8 kf = *(const bf16x8*)(ks + (t * 16 + l15) * LDK + q16 * 8);
                    f32x4 sacc = {0.f, 0.f, 0.f, 0.f};
                    sacc = __builtin_amdgcn_mfma_f32_16x16x32_bf16(kf, qfrag, sacc, 0, 0, 0);
                    const int key_gb = m0 + t * 16 + q16 * 4;
                    short tmp[4];
                    #pragma unroll
                    for (int r = 0; r < 4; ++r) {
                        float sv = sacc[r] * 0.17677669529663687f;
                        float wgt = silu_f(sv * sv);
                        if (key_gb + r > query_g) wgt = 0.f;
                        tmp[r] = f2bfs(wgt);
                    }
                    *(bf16x4*)(scw + l15 * LDSC + t * 16 + q16 * 4) = *(bf16x4*)tmp;
                }
            }
            #pragma unroll
            for (int kt = 0; kt < 2; ++kt) {
                bf16x8 pf = *(const bf16x8*)(scw + l15 * LDSC + kt * 32 + q16 * 8);
                bf16x8 v0 = *(const bf16x8*)(vt + l15 * LDV        + kt * 32 + q16 * 8);
                bf16x8 v1 = *(const bf16x8*)(vt + (16 + l15) * LDV + kt * 32 + q16 * 8);
                o0 = __builtin_amdgcn_mfma_f32_16x16x32_bf16(pf, v0, o0, 0, 0, 0);
                o1 = __builtin_amdgcn_mfma_f32_16x16x32_bf16(pf, v1, o1, 0, 0, 0);
            }
        }
        short* dst = as_part + zz * BSD;
        const int nrow = n0 + w * 16 + q16 * 4;
        #pragma unroll
        for (int r = 0; r < 4; ++r) {
            dst[(b * S + nrow + r) * D + h * HD + l15]      = f2bfs(o0[r]);
            dst[(b * S + nrow + r) * D + h * HD + 16 + l15] = f2bfs(o1[r]);
        }
    } else {
        float* pwf = (float*)smem;                // 1056 f32 = 4224 B
        short* vt  = (short*)(smem + 4224);       // 128*LDV*2 = 18432 B
        const int pid = bid - 1024;
        const int n0  = (pid >> 3) * 32;
        const int sub = pid & 7;
        const int b   = sub >> 1;
        const int z   = sub & 1;
        const int s   = w >> 1;
        const int dh  = w & 1;

        const int base_g = 2016 + z * 1024 - n0;
        for (int i = tid; i < 1055; i += 256) pwf[i] = pos_w[base_g + i];

        f32x4 acc[4];
        #pragma unroll
        for (int dt = 0; dt < 4; ++dt) acc[dt] = (f32x4){0.f, 0.f, 0.f, 0.f};

        int sd[4], sm8[4];
        const short* vp[4];
        #pragma unroll
        for (int i = 0; i < 4; ++i) {
            int e = tid + i * 256;
            sd[i] = e >> 3; sm8[i] = e & 7;
            vp[i] = vtb + (b * D + sd[i]) * S + z * 1024 + sm8[i] * 8;
        }
        bf16x8 vreg[4];
        #pragma unroll
        for (int i = 0; i < 4; ++i) vreg[i] = *(const bf16x8*)(vp[i]);

        for (int mt = 0; mt < 16; ++mt) {
            __syncthreads();
            #pragma unroll
            for (int i = 0; i < 4; ++i)
                *(bf16x8*)(vt + sd[i] * LDV + sm8[i] * 8) = vreg[i];
            __syncthreads();
            if (mt + 1 < 16) {
                #pragma unroll
                for (int i = 0; i < 4; ++i)
                    vreg[i] = *(const bf16x8*)(vp[i] + (mt + 1) * 64);
            }
            #pragma unroll
            for (int kt = 0; kt < 2; ++kt) {
                const int idx0 = mt * 64 + kt * 32 + q16 * 8 + 31 - s * 16 - l15;
                union { unsigned int u[4]; bf16x8 v; } cvt;
                #pragma unroll
                for (int p = 0; p < 4; ++p) {
                    unsigned int a0 = __float_as_uint(pwf[idx0 + 2 * p])     + 0x8000u;
                    unsigned int a1 = __float_as_uint(pwf[idx0 + 2 * p + 1]) + 0x8000u;
                    cvt.u[p] = __builtin_amdgcn_perm(a1, a0, 0x07060302u);
                }
                bf16x8 af = cvt.v;
                #pragma unroll
                for (int dt = 0; dt < 4; ++dt) {
                    bf16x8 bv = *(const bf16x8*)(vt + (dh * 64 + dt * 16 + l15) * LDV + kt * 32 + q16 * 8);
                    acc[dt] = __builtin_amdgcn_mfma_f32_16x16x32_bf16(af, bv, acc[dt], 0, 0, 0);
                }
            }
        }
        short* dst = ap + z * BSD;
        const int nrow = n0 + s * 16 + q16 * 4;
        #pragma unroll
        for (int dt = 0; dt < 4; ++dt)
            #pragma unroll
            for (int r = 0; r < 4; ++r)
                dst[(b * S + nrow + r) * D + dh * 64 + dt * 16 + l15] = f2bfs(acc[dt][r]);
    }
}

// ---------------------------------------------------------------------------
// Kernel 3 (MFMA): 1024 blocks x 8 rows. LN -> h bf16 LDS -> h@Wf^T -> relu+x.
// ---------------------------------------------------------------------------
__global__ __launch_bounds__(256) void k_final(
    const short* __restrict__ as_part, const short* __restrict__ ap,
    const short* __restrict__ ub, const short* __restrict__ wft,
    const float* __restrict__ gamma, const float* __restrict__ beta,
    const float* __restrict__ bfb,
    const float* __restrict__ x, float* __restrict__ out)
{
    __shared__ short hsb[16 * LDH] __attribute__((aligned(16)));
    const int tid  = threadIdx.x;
    const int row0 = blockIdx.x * 8;

    for (int i = tid; i < 8 * LDH; i += 256) hsb[8 * LDH + i] = 0;

    {
        const int row = tid >> 5;
        const int c   = tid & 31;
        float av[8];
        float s1 = 0.f, s2 = 0.f;
        #pragma unroll
        for (int j = 0; j < 8; ++j) {
            int col = c + j * 32;
            float v_;
            if (col < 128)
                v_ = bfs2f(as_part[(row0 + row) * D + col]) +
                     bfs2f(as_part[BSD + (row0 + row) * D + col]);
            else {
                int c2 = col - 128;
                v_ = bfs2f(ap[(row0 + row) * D + c2]) +
                     bfs2f(ap[BSD + (row0 + row) * D + c2]);
            }
            av[j] = v_;
            s1 += v_;
            s2 += v_ * v_;
        }
        #pragma unroll
        for (int off = 1; off < 32; off <<= 1) {
            s1 += __shfl_xor(s1, off);
            s2 += __shfl_xor(s2, off);
        }
        float mu  = s1 * (1.f / 256.f);
        float var = s2 * (1.f / 256.f) - mu * mu;
        float rs  = rsqrtf(var + 1e-3f);
        #pragma unroll
        for (int j = 0; j < 8; ++j) {
            int col = c + j * 32;
            float an = (av[j] - mu) * rs * gamma[col] + beta[col];
            float h  = bfs2f(ub[(row0 + row) * D2 + col]) * an;
            hsb[row * LDH + col] = f2bfs(h);
        }
    }
    __syncthreads();

    const int w    = tid >> 6;
    const int lane = tid & 63;
    const int q16  = lane >> 4;
    const int l15  = lane & 15;
    f32x4 o[2];
    o[0] = (f32x4){0.f, 0.f, 0.f, 0.f};
    o[1] = (f32x4){0.f, 0.f, 0.f, 0.f};
    #pragma unroll
    for (int ks = 0; ks < 8; ++ks) {
        bf16x8 af = *(const bf16x8*)(hsb + l15 * LDH + ks * 32 + q16 * 8);
        #pragma unroll
        for (int ci = 0; ci < 2; ++ci) {
            const int ct = w * 2 + ci;
            bf16x8 bfr = *(const bf16x8*)(wft + (ct * 16 + l15) * D2 + ks * 32 + q16 * 8);
            o[ci] = __builtin_amdgcn_mfma_f32_16x16x32_bf16(af, bfr, o[ci], 0, 0, 0);
        }
    }
    if (q16 < 2) {
        #pragma unroll
        for (int ci = 0; ci < 2; ++ci) {
            const int n = (w * 2 + ci) * 16 + l15;
            const float bfv = bfb[n];
            #pragma unroll
            for (int r = 0; r < 4; ++r) {
                const int row = row0 + q16 * 4 + r;
                float oo = o[ci][r] + bfv;
                oo = fmaxf(oo, 0.f);
                oo += x[row * D + n];
                out[row * D + n] = oo;
            }
        }
    }
}

// ---------------------------------------------------------------------------
extern "C" void kernel_launch(void* const* d_in, const int* in_sizes, int n_in,
                              void* d_out, int out_size, void* d_ws, size_t ws_size,
                              hipStream_t stream)
{
    const float* x     = (const float*)d_in[0];
    const float* Wq    = (const float*)d_in[1];
    const float* bq    = (const float*)d_in[2];
    const float* Wk    = (const float*)d_in[3];
    const float* bk    = (const float*)d_in[4];
    const float* Wv    = (const float*)d_in[5];
    const float* bv    = (const float*)d_in[6];
    const float* Wu    = (const float*)d_in[7];
    const float* bu    = (const float*)d_in[8];
    const float* pos_w = (const float*)d_in[9];
    const float* gamma = (const float*)d_in[10];
    const float* beta  = (const float*)d_in[11];
    const float* Wf    = (const float*)d_in[12];
    const float* bfb   = (const float*)d_in[13];
    float* out = (float*)d_out;

    char* p = (char*)d_ws;
    short* qb      = (short*)p;  p += (size_t)BSD * 2;
    short* kb      = (short*)p;  p += (size_t)BSD * 2;
    short* vtb     = (short*)p;  p += (size_t)BSD * 2;
    short* ubuf    = (short*)p;  p += (size_t)2 * BSD * 2;
    short* as_part = (short*)p;  p += (size_t)2 * BSD * 2;
    short* ap      = (short*)p;  p += (size_t)2 * BSD * 2;
    short* wqt     = (short*)p;  p += (size_t)D * D * 2;
    short* wkt     = (short*)p;  p += (size_t)D * D * 2;
    short* wvt     = (short*)p;  p += (size_t)D * D * 2;
    short* wut     = (short*)p;  p += (size_t)D2 * D * 2;
    short* wft     = (short*)p;  p += (size_t)D * D2 * 2;

    k_wt   <<<dim3(448),    256, 0, stream>>>(Wq, Wk, Wv, Wu, Wf, wqt, wkt, wvt, wut, wft);
    k_qkvu <<<dim3(512, 2), 256, 0, stream>>>(x, wqt, wkt, wvt, wut, bq, bk, bv, bu, qb, kb, vtb, ubuf);
    k_mix  <<<dim3(1536),   256, 0, stream>>>(qb, kb, vtb, pos_w, as_part, ap);
    k_final<<<dim3(1024),   256, 0, stream>>>(as_part, ap, ubuf, wft, gamma, beta, bfb, x, out);
}